// Round 11
// baseline (169.343 us; speedup 1.0000x reference)
//
#include <hip/hip_runtime.h>
#include <math.h>

// SupervisedContrastiveLoss (R11): register-resident square tile.
//   row_loss_i = log(S_i) - (h_i . csum[lbl_i] - ||h_i||^2) * invT / pos_cnt_i
//   S_i = sum_{lbl_j != lbl_i} exp(s_ij/T)
// R10 post-mortem: VGPR_Count=128 == sizeof(A-frags) -> compiler NEVER kept A
// resident; it rematerialized A loads every step: 33K steps x 40KB = 1.3GB L2
// traffic ~38us = the invariant ~50-66us gemm across R7-R10 structures.
// R11: amdgpu_waves_per_eu(2,2) pins the budget at 256 VGPR (no remat incentive)
// and the tile shrinks to provably fit: 32-row strips x 32-col steps (square =
// minimal streamed bytes/FLOP). A 64 + B-dbuf 128 + acc 16 + rowS 8 + misc ~241.
// L2 traffic -> ~0.6GB (~17us). Triangle scheme as verified: strip by = rows
// [32by,32by+32), cols [32by,8192) in 32-col steps; t=0 = diagonal 32x32 block
// (both orders computed -> rowS only); t>=1 -> rowS + colS.

#define NROWS 8192
#define NDIM  256
#define NSTEPS_TOTAL 32896        // sum_{by<256} (256 - by)
#define NWAVES 2048
#define INVT 14.285714285714286f  // 1/0.07
#define SC_LOG2E (14.285714285714286f * 1.4426950408889634f)  // invT * log2(e)
#define MASK_BIAS -30000.0f       // exp2 bias for same-label pairs -> exp == 0

typedef __attribute__((ext_vector_type(8))) short short8;
typedef __attribute__((ext_vector_type(4))) float f32x4;

__device__ __forceinline__ unsigned short f2bf(float f) {
    unsigned int u = __float_as_uint(f);
    u = u + 0x7fffu + ((u >> 16) & 1u);     // RNE
    return (unsigned short)(u >> 16);
}
__device__ __forceinline__ float bf2f(unsigned short s) {
    return __uint_as_float(((unsigned int)s) << 16);
}

// ================= prep: normalize -> hA bf16; selfsim; neg=0; csum/cnt partials
__global__ __launch_bounds__(256) void prep_kernel(const float* __restrict__ x,
                                                   const int* __restrict__ labels,
                                                   unsigned short* __restrict__ hA,
                                                   float* __restrict__ selfsim,
                                                   float* __restrict__ neg,
                                                   float* __restrict__ csum_part,
                                                   float* __restrict__ cnt_part,
                                                   int* __restrict__ ticket) {
    __shared__ float sdata[4][2][256];
    __shared__ float cw[4];
    const int tid = threadIdx.x, blk = blockIdx.x;
    const int w = tid >> 6, lane = tid & 63;
    const int row0 = blk * 32;

    float a0[4] = {0.f, 0.f, 0.f, 0.f}, a1[4] = {0.f, 0.f, 0.f, 0.f};
    int c1 = 0;
    for (int i = 0; i < 8; ++i) {
        int row = row0 + w * 8 + i;
        float4 v = *(const float4*)(x + (size_t)row * NDIM + lane * 4);
        float ss = v.x * v.x + v.y * v.y + v.z * v.z + v.w * v.w;
#pragma unroll
        for (int o = 32; o >= 1; o >>= 1) ss += __shfl_xor(ss, o, 64);
        float inv = 1.0f / fmaxf(sqrtf(ss), 1e-12f);
        ushort4 b;
        b.x = f2bf(v.x * inv); b.y = f2bf(v.y * inv);
        b.z = f2bf(v.z * inv); b.w = f2bf(v.w * inv);
        float f0 = bf2f(b.x), f1 = bf2f(b.y), f2 = bf2f(b.z), f3 = bf2f(b.w);
        float s2 = f0 * f0 + f1 * f1 + f2 * f2 + f3 * f3;
#pragma unroll
        for (int o = 32; o >= 1; o >>= 1) s2 += __shfl_xor(s2, o, 64);
        *(ushort4*)(hA + (size_t)row * NDIM + lane * 4) = b;
        if (lane == 0) { selfsim[row] = s2; neg[row] = 0.f; }
        int l = labels[row] & 1;
        c1 += l;
        if (l) { a1[0] += f0; a1[1] += f1; a1[2] += f2; a1[3] += f3; }
        else   { a0[0] += f0; a0[1] += f1; a0[2] += f2; a0[3] += f3; }
    }
#pragma unroll
    for (int k = 0; k < 4; ++k) {
        sdata[w][0][lane * 4 + k] = a0[k];
        sdata[w][1][lane * 4 + k] = a1[k];
    }
    if (lane == 0) cw[w] = (float)c1;
    __syncthreads();
    float s0 = sdata[0][0][tid] + sdata[1][0][tid] + sdata[2][0][tid] + sdata[3][0][tid];
    float s1 = sdata[0][1][tid] + sdata[1][1][tid] + sdata[2][1][tid] + sdata[3][1][tid];
    csum_part[blk * 512 + tid] = s0;
    csum_part[blk * 512 + 256 + tid] = s1;
    if (tid == 0) {
        float c = cw[0] + cw[1] + cw[2] + cw[3];
        cnt_part[blk * 2 + 1] = c;
        cnt_part[blk * 2 + 0] = 32.0f - c;
        if (blk == 0) ticket[0] = 0;
    }
}

// ================= csum finalize (parallel): blocks 0..63 -> 8 dims each,
// 32 threads/dim, 8 parallel strided loads + shuffle reduce. Block 64 -> cnt.
__global__ __launch_bounds__(256) void csumfin_kernel(const float* __restrict__ csum_part,
                                                      const float* __restrict__ cnt_part,
                                                      float* __restrict__ csum,
                                                      float* __restrict__ cnt) {
    const int tid = threadIdx.x, blk = blockIdx.x;
    if (blk < 64) {
        const int dim = blk * 8 + (tid >> 5);    // 0..511 (class*256+d folded)
        const int p = tid & 31;
        float s = 0.f;
#pragma unroll
        for (int k = 0; k < 8; ++k)
            s += csum_part[(size_t)(p + k * 32) * 512 + dim];
#pragma unroll
        for (int o = 1; o < 32; o <<= 1) s += __shfl_xor(s, o, 64);
        if (p == 0) csum[dim] = s;
    } else {
        __shared__ float sd[2][256];
        float c0 = cnt_part[tid * 2], c1 = cnt_part[tid * 2 + 1];
        sd[0][tid] = c0; sd[1][tid] = c1;
        __syncthreads();
        for (int o = 128; o > 0; o >>= 1) {
            if (tid < o) { sd[0][tid] += sd[0][tid + o]; sd[1][tid] += sd[1][tid + o]; }
            __syncthreads();
        }
        if (tid == 0) { cnt[0] = sd[0][0]; cnt[1] = sd[1][0]; }
    }
}

// ================= LDS-free triangle GEMM: 32-row strips, 32-col steps,
// A resident (64 VGPR), B double-buffered (128 VGPR), waves/EU pinned to 2.
__global__ __launch_bounds__(64)
__attribute__((amdgpu_waves_per_eu(2, 2)))
void gemm_kernel(const unsigned short* __restrict__ hA,
                 const int* __restrict__ labels,
                 float* __restrict__ neg) {
    const int lane = threadIdx.x;
    const int quad = lane >> 4, l15 = lane & 15;
    const int wgid = blockIdx.x;
    const int s0 = (int)((long long)wgid * NSTEPS_TOTAL / NWAVES);
    const int s1 = (int)((long long)(wgid + 1) * NSTEPS_TOTAL / NWAVES);
    if (s0 >= s1) return;

    // steps before strip by: cum(by) = 256*by - by*(by-1)/2
    int by = 0;
    while (by < 255 && (256 * (by + 1) - (by + 1) * by / 2) <= s0) ++by;
    int t = s0 - (256 * by - by * (by - 1) / 2);

    short8 a[2][8];
    unsigned rl;
    float rowS[2][4];

    auto loadStrip = [&](int row0) {
#pragma unroll
        for (int mt = 0; mt < 2; ++mt)
#pragma unroll
            for (int ki = 0; ki < 8; ++ki)
                a[mt][ki] = *(const short8*)(hA +
                    (size_t)(row0 + mt * 16 + l15) * NDIM + ki * 32 + quad * 8);
        rl = 0;
#pragma unroll
        for (int mt = 0; mt < 2; ++mt)
#pragma unroll
            for (int r = 0; r < 4; ++r)
                rl |= (unsigned)(labels[row0 + mt * 16 + quad * 4 + r] & 1) << (mt * 4 + r);
#pragma unroll
        for (int mt = 0; mt < 2; ++mt)
#pragma unroll
            for (int r = 0; r < 4; ++r) rowS[mt][r] = 0.f;
    };

    auto flushRowS = [&](int row0) {
#pragma unroll
        for (int o = 1; o < 16; o <<= 1)
#pragma unroll
            for (int mt = 0; mt < 2; ++mt)
#pragma unroll
                for (int r = 0; r < 4; ++r)
                    rowS[mt][r] += __shfl_xor(rowS[mt][r], o, 64);
        if (l15 == 0) {
#pragma unroll
            for (int mt = 0; mt < 2; ++mt)
#pragma unroll
                for (int r = 0; r < 4; ++r)
                    atomicAdd(&neg[row0 + mt * 16 + quad * 4 + r], rowS[mt][r]);
        }
    };

    loadStrip(by * 32);

    // B double-buffer: [pp][tile][ki]
    short8 b[2][2][8];
    int cl0[2], cl1[2];
    {
        const int col0 = by * 32 + t * 32;
        const unsigned short* bp = hA + (size_t)(col0 + l15) * NDIM + quad * 8;
#pragma unroll
        for (int ki = 0; ki < 8; ++ki) {
            b[0][0][ki] = *(const short8*)(bp + ki * 32);
            b[0][1][ki] = *(const short8*)(bp + 16 * NDIM + ki * 32);
        }
        cl0[0] = labels[col0 + l15] & 1;
        cl1[0] = labels[col0 + 16 + l15] & 1;
    }

    int s = s0;

#define GEMM_STEP(PP)                                                                   \
    {                                                                                   \
        const int nst = 256 - by;                                                       \
        const bool strip_end = (t == nst - 1);                                          \
        const int byn = strip_end ? by + 1 : by;                                        \
        const int tn  = strip_end ? 0 : t + 1;                                          \
        const bool pf = (s + 1 < s1);                                                   \
        if (pf) {                                                                       \
            const int c0n = byn * 32 + tn * 32;                                         \
            const unsigned short* bp = hA + (size_t)(c0n + l15) * NDIM + quad * 8;      \
            _Pragma("unroll")                                                           \
            for (int ki = 0; ki < 8; ++ki) {                                            \
                b[PP ^ 1][0][ki] = *(const short8*)(bp + ki * 32);                      \
                b[PP ^ 1][1][ki] = *(const short8*)(bp + 16 * NDIM + ki * 32);          \
            }                                                                           \
            cl0[PP ^ 1] = labels[c0n + l15] & 1;                                        \
            cl1[PP ^ 1] = labels[c0n + 16 + l15] & 1;                                   \
        }                                                                               \
        const int col0 = by * 32 + t * 32;                                              \
        const unsigned diff0 = rl ^ (cl0[PP] ? 0xFFu : 0u);                             \
        const unsigned diff1 = rl ^ (cl1[PP] ? 0xFFu : 0u);                             \
        f32x4 acc[2][2];                                                                \
        _Pragma("unroll")                                                               \
        for (int mt = 0; mt < 2; ++mt) {                                                \
            acc[mt][0] = (f32x4){0.f, 0.f, 0.f, 0.f};                                   \
            acc[mt][1] = (f32x4){0.f, 0.f, 0.f, 0.f};                                   \
        }                                                                               \
        _Pragma("unroll")                                                               \
        for (int ki = 0; ki < 8; ++ki) {                                                \
            _Pragma("unroll")                                                           \
            for (int mt = 0; mt < 2; ++mt) {                                            \
                acc[mt][0] = __builtin_amdgcn_mfma_f32_16x16x32_bf16(a[mt][ki],         \
                                 b[PP][0][ki], acc[mt][0], 0, 0, 0);                    \
                acc[mt][1] = __builtin_amdgcn_mfma_f32_16x16x32_bf16(a[mt][ki],         \
                                 b[PP][1][ki], acc[mt][1], 0, 0, 0);                    \
            }                                                                           \
        }                                                                               \
        float colS0 = 0.f, colS1 = 0.f;                                                 \
        _Pragma("unroll")                                                               \
        for (int mt = 0; mt < 2; ++mt)                                                  \
            _Pragma("unroll")                                                           \
            for (int r = 0; r < 4; ++r) {                                               \
                float bias0 = ((diff0 >> (mt * 4 + r)) & 1u) ? 0.f : MASK_BIAS;         \
                float bias1 = ((diff1 >> (mt * 4 + r)) & 1u) ? 0.f : MASK_BIAS;         \
                float e0 = exp2f(fmaf(acc[mt][0][r], SC_LOG2E, bias0));                 \
                float e1 = exp2f(fmaf(acc[mt][1][r], SC_LOG2E, bias1));                 \
                rowS[mt][r] += e0 + e1;                                                 \
                colS0 += e0;                                                            \
                colS1 += e1;                                                            \
            }                                                                           \
        if (t >= 1) {                                                                   \
            colS0 += __shfl_xor(colS0, 16, 64);                                         \
            colS0 += __shfl_xor(colS0, 32, 64);                                         \
            colS1 += __shfl_xor(colS1, 16, 64);                                         \
            colS1 += __shfl_xor(colS1, 32, 64);                                         \
            if (quad == 0) {                                                            \
                atomicAdd(&neg[col0 + l15], colS0);                                     \
                atomicAdd(&neg[col0 + 16 + l15], colS1);                                \
            }                                                                           \
        }                                                                               \
        if (strip_end || !pf) {                                                         \
            flushRowS(by * 32);                                                         \
            if (pf) loadStrip(byn * 32);                                                \
        }                                                                               \
        by = byn; t = tn; ++s;                                                          \
        if (!pf) break;                                                                 \
    }

    while (true) {
        GEMM_STEP(0)
        GEMM_STEP(1)
    }
#undef GEMM_STEP
}

// ================= rowloss + ticketed finalize (last block writes out)
__global__ __launch_bounds__(256) void rowloss_kernel(const unsigned short* __restrict__ hA,
                                                      const int* __restrict__ labels,
                                                      const float* __restrict__ neg,
                                                      const float* __restrict__ selfsim,
                                                      const float* __restrict__ csum,
                                                      const float* __restrict__ cnt,
                                                      float* __restrict__ pbuf,
                                                      int* __restrict__ ticket,
                                                      float* __restrict__ out) {
    __shared__ float csumS[2][256];
    __shared__ float red[8];
    __shared__ int lastFlag;
    const int tid = threadIdx.x, blk = blockIdx.x;
    const int w = tid >> 6, lane = tid & 63;

    csumS[0][tid] = csum[tid];
    csumS[1][tid] = csum[256 + tid];
    __syncthreads();
    const float c0v = cnt[0], c1v = cnt[1];

    const int row0 = blk * 128;
    float wsum = 0.f, wcnt = 0.f;
    for (int i = 0; i < 32; ++i) {
        int row = row0 + w * 32 + i;
        int l = labels[row] & 1;
        ushort4 hv = *(const ushort4*)(hA + (size_t)row * NDIM + lane * 4);
        const float* cv = &csumS[l][lane * 4];
        float dot = bf2f(hv.x) * cv[0] + bf2f(hv.y) * cv[1] +
                    bf2f(hv.z) * cv[2] + bf2f(hv.w) * cv[3];
#pragma unroll
        for (int o = 32; o >= 1; o >>= 1) dot += __shfl_xor(dot, o, 64);
        if (lane == 0) {
            float pc = (l ? c1v : c0v) - 1.0f;
            float S = neg[row];
            if (pc > 0.5f) {
                wcnt += 1.f;
                if (S > 0.f)
                    wsum += logf(S) - (dot - selfsim[row]) * INVT / pc;
            }
        }
    }
    if (lane == 0) { red[w] = wsum; red[4 + w] = wcnt; }
    __syncthreads();
    if (tid == 0) {
        atomicExch(&pbuf[blk],      red[0] + red[1] + red[2] + red[3]);
        atomicExch(&pbuf[64 + blk], red[4] + red[5] + red[6] + red[7]);
        __threadfence();
        int old = atomicAdd(ticket, 1);
        lastFlag = (old == 63) ? 1 : 0;
    }
    __syncthreads();
    if (lastFlag && tid < 64) {
        __threadfence();
        float v = atomicAdd(&pbuf[tid], 0.0f);        // device-scope atomic read
        float c = atomicAdd(&pbuf[64 + tid], 0.0f);
#pragma unroll
        for (int o = 32; o >= 1; o >>= 1) {
            v += __shfl_xor(v, o, 64);
            c += __shfl_xor(c, o, 64);
        }
        if (tid == 0) out[0] = (c > 0.f) ? v / c : 0.f;
    }
}

extern "C" void kernel_launch(void* const* d_in, const int* in_sizes, int n_in,
                              void* d_out, int out_size, void* d_ws, size_t ws_size,
                              hipStream_t stream) {
    const float* x = (const float*)d_in[0];
    const int* labels = (const int*)d_in[1];

    unsigned short* hA = (unsigned short*)d_ws;              // N*D bf16 = 4 MB
    float* wsf       = (float*)d_ws;
    float* selfsim   = wsf + (size_t)NROWS * NDIM / 2;       // 8192
    float* neg       = selfsim + NROWS;                      // 8192
    float* csum_part = neg + NROWS;                          // 256*512
    float* cnt_part  = csum_part + 256 * 512;                // 512
    float* csum      = cnt_part + 512;                       // 512
    float* cnt       = csum + 512;                           // 2
    float* pbuf      = cnt + 2;                              // 128
    int*   ticket    = (int*)(pbuf + 128);                   // 1

    prep_kernel<<<256, 256, 0, stream>>>(x, labels, hA, selfsim, neg, csum_part, cnt_part, ticket);
    csumfin_kernel<<<65, 256, 0, stream>>>(csum_part, cnt_part, csum, cnt);
    gemm_kernel<<<NWAVES, 64, 0, stream>>>(hA, labels, neg);
    rowloss_kernel<<<64, 256, 0, stream>>>(hA, labels, neg, selfsim, csum, cnt,
                                           pbuf, ticket, (float*)d_out);
}